// Round 2
// baseline (3056.190 us; speedup 1.0000x reference)
//
#include <hip/hip_runtime.h>
#include <hip/hip_bf16.h>
#include <math.h>

#define BATCH 32
#define TSEQ  64
#define KATTR 5
#define VOCAB 32000
#define DE    300
#define DA    300
#define DI    2048
#define HDIM  512
#define G4    2048            // 4*H
#define NBLK  64              // persistent scan blocks

// ---------------------------------------------------------------- utility
__global__ void zero_kernel(float* __restrict__ p, int n) {
    int i = blockIdx.x * blockDim.x + threadIdx.x;
    if (i < n) p[i] = 0.f;
}

// ---------------------------------------------------------------- K1: mean attr embedding
__global__ void mean_attr_kernel(const int* __restrict__ topk,
                                 const float* __restrict__ attr_emb,
                                 float* __restrict__ mean_attr) {
    int b = blockIdx.x;
    int tid = threadIdx.x;
    if (tid < DA) {
        float s = 0.f;
        #pragma unroll
        for (int q = 0; q < KATTR; ++q) {
            int a = topk[b * KATTR + q];
            s += attr_emb[(size_t)a * DA + tid];
        }
        mean_attr[b * DA + tid] = s / (float)KATTR;
    }
}

// ---------------------------------------------------------------- K2: zf[b][j] = bias + img@Wimg + mean_attr@Wattr
__launch_bounds__(256)
__global__ void zf_kernel(const float* __restrict__ img,
                          const float* __restrict__ mean_attr,
                          const float* __restrict__ Wk,
                          const float* __restrict__ bias,
                          float* __restrict__ zf) {
    int b = blockIdx.y;
    int j = blockIdx.x * 256 + threadIdx.x;
    float acc = bias[j];
    const float* wimg = Wk + (size_t)DE * G4 + j;
    const float* irow = img + b * DI;
    #pragma unroll 8
    for (int k = 0; k < DI; ++k) acc += irow[k] * wimg[(size_t)k * G4];
    const float* wattr = Wk + (size_t)(DE + DI) * G4 + j;
    const float* arow = mean_attr + b * DA;
    #pragma unroll 4
    for (int k = 0; k < DA; ++k) acc += arow[k] * wattr[(size_t)k * G4];
    zf[b * G4 + j] = acc;
}

// ---------------------------------------------------------------- z_pre GEMM (transposed output)
// z_preT[n][m] = sum_k word_emb[seq[m]][k]*Wk[k][n] + zf[m>>6][n]
__launch_bounds__(256)
__global__ void gemm_zpreT(const float* __restrict__ A,      // word_emb
                           const int* __restrict__ gidx,     // seq (row gather)
                           const float* __restrict__ Bm,     // Wk (word rows on top)
                           const float* __restrict__ zf,
                           float* __restrict__ CT) {
    __shared__ __align__(16) float As[16][68];
    __shared__ __align__(16) float Bs[16][68];
    const int tid = threadIdx.x;
    const int n0 = blockIdx.x * 64;
    const int m0 = blockIdx.y * 64;
    const int tx = tid & 15, ty = tid >> 4;
    const int ar  = tid >> 2;
    const int akq = (tid & 3) << 2;
    const int bkr = tid >> 4;
    const int bc  = (tid & 15) << 2;
    const int K = DE, lda = DE, N = G4, M = BATCH * TSEQ;

    size_t arow = (size_t)gidx[m0 + ar] * (size_t)lda;

    float a00=0,a01=0,a02=0,a03=0, a10=0,a11=0,a12=0,a13=0;
    float a20=0,a21=0,a22=0,a23=0, a30=0,a31=0,a32=0,a33=0;

    for (int k0 = 0; k0 < K; k0 += 16) {
        int ka = k0 + akq;
        float4 av;
        if (ka + 4 <= K) {
            av = *(const float4*)(A + arow + ka);
        } else {
            av.x = (ka + 0 < K) ? A[arow + ka + 0] : 0.f;
            av.y = (ka + 1 < K) ? A[arow + ka + 1] : 0.f;
            av.z = (ka + 2 < K) ? A[arow + ka + 2] : 0.f;
            av.w = (ka + 3 < K) ? A[arow + ka + 3] : 0.f;
        }
        As[akq + 0][ar] = av.x;
        As[akq + 1][ar] = av.y;
        As[akq + 2][ar] = av.z;
        As[akq + 3][ar] = av.w;

        int kb = k0 + bkr;
        float4 bv;
        if (kb < K) bv = *(const float4*)(Bm + (size_t)kb * N + n0 + bc);
        else { bv.x = bv.y = bv.z = bv.w = 0.f; }
        *(float4*)&Bs[bkr][bc] = bv;

        __syncthreads();
        #pragma unroll
        for (int kk = 0; kk < 16; ++kk) {
            const float4 a4 = *(const float4*)&As[kk][ty << 2];
            const float4 b4 = *(const float4*)&Bs[kk][tx << 2];
            a00 += a4.x * b4.x; a01 += a4.x * b4.y; a02 += a4.x * b4.z; a03 += a4.x * b4.w;
            a10 += a4.y * b4.x; a11 += a4.y * b4.y; a12 += a4.y * b4.z; a13 += a4.y * b4.w;
            a20 += a4.z * b4.x; a21 += a4.z * b4.y; a22 += a4.z * b4.z; a23 += a4.z * b4.w;
            a30 += a4.w * b4.x; a31 += a4.w * b4.y; a32 += a4.w * b4.z; a33 += a4.w * b4.w;
        }
        __syncthreads();
    }

    float accs[4][4] = {{a00,a01,a02,a03},{a10,a11,a12,a13},{a20,a21,a22,a23},{a30,a31,a32,a33}};
    const float* zrow = zf + (size_t)(m0 >> 6) * N;
    const int mb = m0 + (ty << 2);
    #pragma unroll
    for (int jj = 0; jj < 4; ++jj) {
        int n = n0 + (tx << 2) + jj;
        float zadd = zrow[n];
        float4 o;
        o.x = accs[0][jj] + zadd;
        o.y = accs[1][jj] + zadd;
        o.z = accs[2][jj] + zadd;
        o.w = accs[3][jj] + zadd;
        *(float4*)(CT + (size_t)n * M + mb) = o;
    }
}

// ---------------------------------------------------------------- row compaction list
__global__ void build_rows(const int* __restrict__ lengths,
                           int* __restrict__ rowlist, int* __restrict__ mact) {
    __shared__ int len[BATCH];
    __shared__ int off[BATCH + 1];
    int tid = threadIdx.x;
    if (tid < BATCH) len[tid] = lengths[tid];
    __syncthreads();
    if (tid == 0) {
        int s = 0;
        for (int b = 0; b < BATCH; ++b) { off[b] = s; s += len[b]; }
        off[BATCH] = s;
        *mact = s;
    }
    __syncthreads();
    int total = off[BATCH];
    for (int i = tid; i < BATCH * TSEQ; i += 256) {
        int b = i >> 6, t = i & 63;
        if (t < len[b]) rowlist[off[b] + t] = i;
    }
    for (int i = tid; i < BATCH * TSEQ; i += 256) {
        if (i >= total) rowlist[i] = 0;
    }
}

// ---------------------------------------------------------------- grid barrier (monotone counter)
__device__ __forceinline__ void gridbar(int* __restrict__ cnt, int target) {
    __syncthreads();
    if (threadIdx.x == 0) {
        __threadfence();
        atomicAdd(cnt, 1);
        while (__hip_atomic_load(cnt, __ATOMIC_ACQUIRE, __HIP_MEMORY_SCOPE_AGENT) < target) {
            __builtin_amdgcn_s_sleep(2);
        }
    }
    __syncthreads();
}

// ---------------------------------------------------------------- persistent LSTM scan
// 64 blocks x 256 thr. Block owns kout range [blk*8, blk*8+8) across all 4 gates
// (32 j-cols). Wh slice lives in VGPRs (64/thread). h double-buffered in hglob
// [slot][k][b]; c register-resident in gate threads.
__launch_bounds__(256, 1)
__global__ void lstm_persist(const float* __restrict__ zpreT,
                             const float* __restrict__ Wk,
                             const int* __restrict__ lengths,
                             float* __restrict__ hglob,    // [2][512][32]
                             float* __restrict__ h_seq,    // [2048][512]
                             int* __restrict__ bar) {
    const int tid = threadIdx.x;
    const int koutbase = blockIdx.x * 8;

    __shared__ __align__(16) float hs[BATCH][516];   // [b][k] padded
    __shared__ float zred[16][32][9];                // [kgrp][jcol][b-chunk pad]
    __shared__ float zfull[32][33];                  // [jcol][b]

    // z-phase mapping
    const int jslot = tid & 15;
    const int kgrp  = tid >> 4;                      // 16 groups, 32 k each (interleaved)
    const int g     = jslot >> 2;
    const int j0    = g * HDIM + koutbase + ((jslot & 3) << 1);

    // Wh slice -> registers. k(i) = kgrp*4 + (i>>2)*64 + (i&3)
    float w0[32], w1[32];
    #pragma unroll
    for (int i = 0; i < 32; ++i) {
        int k = (kgrp << 2) + ((i >> 2) << 6) + (i & 3);
        const float* wr = Wk + (size_t)(DE + DI + DA + k) * G4;
        w0[i] = wr[j0];
        w1[i] = wr[j0 + 1];
    }

    // gate-phase mapping
    const int gb  = tid & 31;
    const int gk  = tid >> 5;            // 0..7
    const int gkk = koutbase + gk;       // global k
    const int glen = lengths[gb];
    float creg = 0.f;

    int barcnt = 0;
    for (int t = 0; t < TSEQ; ++t) {
        // stage h (slot t&1) into LDS; coherent loads (skip stale L1)
        const float* hsl = hglob + (size_t)(t & 1) * (HDIM * BATCH);
        for (int i = tid; i < HDIM * BATCH; i += 256) {
            float v = __hip_atomic_load(hsl + i, __ATOMIC_RELAXED, __HIP_MEMORY_SCOPE_AGENT);
            hs[i & 31][i >> 5] = v;      // i = k*32 + b
        }
        // prefetch z_pre for gate phase (independent of h)
        const int m = gb * TSEQ + t;
        float zp0 = zpreT[(size_t)(0 * HDIM + gkk) * (BATCH * TSEQ) + m];
        float zp1 = zpreT[(size_t)(1 * HDIM + gkk) * (BATCH * TSEQ) + m];
        float zp2 = zpreT[(size_t)(2 * HDIM + gkk) * (BATCH * TSEQ) + m];
        float zp3 = zpreT[(size_t)(3 * HDIM + gkk) * (BATCH * TSEQ) + m];
        __syncthreads();

        // z = h @ Wh for this block's 32 cols, 4 chunks of 8 batches
        for (int ch = 0; ch < 4; ++ch) {
            float acc0[8], acc1[8];
            #pragma unroll
            for (int bb = 0; bb < 8; ++bb) { acc0[bb] = 0.f; acc1[bb] = 0.f; }
            #pragma unroll
            for (int iq = 0; iq < 8; ++iq) {
                int kq = (kgrp << 2) + (iq << 6);
                #pragma unroll
                for (int bb = 0; bb < 8; ++bb) {
                    const float4 hq = *(const float4*)&hs[(ch << 3) + bb][kq];
                    acc0[bb] += w0[iq*4+0]*hq.x + w0[iq*4+1]*hq.y + w0[iq*4+2]*hq.z + w0[iq*4+3]*hq.w;
                    acc1[bb] += w1[iq*4+0]*hq.x + w1[iq*4+1]*hq.y + w1[iq*4+2]*hq.z + w1[iq*4+3]*hq.w;
                }
            }
            const int jc0 = (jslot << 1), jc1 = jc0 + 1;
            #pragma unroll
            for (int bb = 0; bb < 8; ++bb) {
                zred[kgrp][jc0][bb] = acc0[bb];
                zred[kgrp][jc1][bb] = acc1[bb];
            }
            __syncthreads();
            {   // reduce 16 kgrp partials
                int jcol = tid >> 3, bb = tid & 7;
                float s = 0.f;
                #pragma unroll
                for (int kg = 0; kg < 16; ++kg) s += zred[kg][jcol][bb];
                zfull[jcol][(ch << 3) + bb] = s;
            }
            __syncthreads();
        }

        // gate math: thread (gk, gb)
        float zi = zfull[0 * 8 + gk][gb] + zp0;
        float zF = zfull[1 * 8 + gk][gb] + zp1;
        float zg = zfull[2 * 8 + gk][gb] + zp2;
        float zo = zfull[3 * 8 + gk][gb] + zp3;
        float si = 1.f / (1.f + expf(-zi));
        float sf = 1.f / (1.f + expf(-zF));
        float so = 1.f / (1.f + expf(-zo));
        creg = sf * creg + si * tanhf(zg);
        float hnew = so * tanhf(creg);
        hglob[(size_t)((t + 1) & 1) * (HDIM * BATCH) + gkk * BATCH + gb] = hnew;
        h_seq[(size_t)m * HDIM + gkk] = (t < glen) ? hnew : 0.f;

        if (t < TSEQ - 1) {
            barcnt += NBLK;
            gridbar(bar, barcnt);
        }
    }
}

// ---------------------------------------------------------------- fill masked logits rows with bias
__launch_bounds__(256)
__global__ void fill_masked(const int* __restrict__ lengths,
                            const float* __restrict__ blog,
                            float* __restrict__ logits) {
    int row = blockIdx.x;
    int b = row >> 6, t = row & 63;
    if (t < lengths[b]) return;
    float* p = logits + (size_t)row * VOCAB;
    for (int v = threadIdx.x * 4; v < VOCAB; v += 256 * 4) {
        float4 o;
        o.x = blog[v + 0]; o.y = blog[v + 1]; o.z = blog[v + 2]; o.w = blog[v + 3];
        *(float4*)(p + v) = o;
    }
}

// ---------------------------------------------------------------- logits GEMM over compacted rows
// A row & C row both gathered via rowlist; tiles past *mact exit early.
__launch_bounds__(256)
__global__ void gemm_logits(const float* __restrict__ A,      // h_seq
                            const int* __restrict__ rowlist,
                            const int* __restrict__ mactp,
                            const float* __restrict__ Bm,     // W_logits
                            const float* __restrict__ blog,
                            float* __restrict__ C) {
    const int Mact = *mactp;
    const int m0 = blockIdx.y * 64;
    if (m0 >= Mact) return;
    __shared__ __align__(16) float As[16][68];
    __shared__ __align__(16) float Bs[16][68];
    const int tid = threadIdx.x;
    const int n0 = blockIdx.x * 64;
    const int tx = tid & 15, ty = tid >> 4;
    const int ar  = tid >> 2;
    const int akq = (tid & 3) << 2;
    const int bkr = tid >> 4;
    const int bc  = (tid & 15) << 2;
    const int K = HDIM, N = VOCAB;

    size_t arow = (size_t)rowlist[m0 + ar] * (size_t)HDIM;

    float a00=0,a01=0,a02=0,a03=0, a10=0,a11=0,a12=0,a13=0;
    float a20=0,a21=0,a22=0,a23=0, a30=0,a31=0,a32=0,a33=0;

    for (int k0 = 0; k0 < K; k0 += 16) {
        float4 av = *(const float4*)(A + arow + k0 + akq);
        As[akq + 0][ar] = av.x;
        As[akq + 1][ar] = av.y;
        As[akq + 2][ar] = av.z;
        As[akq + 3][ar] = av.w;
        float4 bv = *(const float4*)(Bm + (size_t)(k0 + bkr) * N + n0 + bc);
        *(float4*)&Bs[bkr][bc] = bv;
        __syncthreads();
        #pragma unroll
        for (int kk = 0; kk < 16; ++kk) {
            const float4 a4 = *(const float4*)&As[kk][ty << 2];
            const float4 b4 = *(const float4*)&Bs[kk][tx << 2];
            a00 += a4.x * b4.x; a01 += a4.x * b4.y; a02 += a4.x * b4.z; a03 += a4.x * b4.w;
            a10 += a4.y * b4.x; a11 += a4.y * b4.y; a12 += a4.y * b4.z; a13 += a4.y * b4.w;
            a20 += a4.z * b4.x; a21 += a4.z * b4.y; a22 += a4.z * b4.z; a23 += a4.z * b4.w;
            a30 += a4.w * b4.x; a31 += a4.w * b4.y; a32 += a4.w * b4.z; a33 += a4.w * b4.w;
        }
        __syncthreads();
    }

    float accs[4][4] = {{a00,a01,a02,a03},{a10,a11,a12,a13},{a20,a21,a22,a23},{a30,a31,a32,a33}};
    const int n = n0 + (tx << 2);
    #pragma unroll
    for (int i = 0; i < 4; ++i) {
        int m = m0 + (ty << 2) + i;
        if (m < Mact) {
            int rm = rowlist[m];
            float4 o;
            o.x = accs[i][0] + blog[n + 0];
            o.y = accs[i][1] + blog[n + 1];
            o.z = accs[i][2] + blog[n + 2];
            o.w = accs[i][3] + blog[n + 3];
            *(float4*)(C + (size_t)rm * VOCAB + n) = o;
        }
    }
}

// ---------------------------------------------------------------- argmax per row (first occurrence)
__launch_bounds__(256)
__global__ void argmax_kernel(const float* __restrict__ logits, float* __restrict__ outa) {
    const int row = blockIdx.x;
    const int tid = threadIdx.x;
    const float* p = logits + (size_t)row * VOCAB;
    float bv = -INFINITY; int bi = VOCAB;
    for (int v = tid; v < VOCAB; v += 256) {
        float x = p[v];
        if (x > bv) { bv = x; bi = v; }
    }
    __shared__ float sv[256];
    __shared__ int   si[256];
    sv[tid] = bv; si[tid] = bi;
    __syncthreads();
    for (int s = 128; s > 0; s >>= 1) {
        if (tid < s) {
            if (sv[tid + s] > sv[tid] || (sv[tid + s] == sv[tid] && si[tid + s] < si[tid])) {
                sv[tid] = sv[tid + s]; si[tid] = si[tid + s];
            }
        }
        __syncthreads();
    }
    if (tid == 0) outa[row] = (float)si[0];
}

// ---------------------------------------------------------------- launcher
extern "C" void kernel_launch(void* const* d_in, const int* in_sizes, int n_in,
                              void* d_out, int out_size, void* d_ws, size_t ws_size,
                              hipStream_t stream) {
    const int*   topk     = (const int*)d_in[0];
    const float* img      = (const float*)d_in[1];
    const int*   seq      = (const int*)d_in[2];
    const int*   lengths  = (const int*)d_in[3];
    const float* word_emb = (const float*)d_in[4];
    const float* attr_emb = (const float*)d_in[5];
    const float* Wk       = (const float*)d_in[6];
    const float* bias     = (const float*)d_in[7];
    const float* Wlog     = (const float*)d_in[8];
    const float* blog     = (const float*)d_in[9];

    float* out_logits = (float*)d_out;
    float* out_argmax = out_logits + (size_t)BATCH * TSEQ * VOCAB;

    // ws layout (floats): mean_attr | zf | h_seq | hglob(2 slots) | bar(2 ints) | rowlist | mact
    float* ws        = (float*)d_ws;
    float* mean_attr = ws;
    float* zf        = mean_attr + BATCH * DA;
    float* h_seq     = zf + BATCH * G4;
    float* hglob     = h_seq + (size_t)BATCH * TSEQ * HDIM;
    int*   bar       = (int*)(hglob + 2 * HDIM * BATCH);
    int*   rowlist   = bar + 2;
    int*   mact      = rowlist + BATCH * TSEQ;
    // z_preT [2048 j][2048 rows] staged in d_out's logits region; consumed by the
    // scan before fill/logits overwrite it.
    float* z_preT    = out_logits;

    // zero hglob (both slots) + barrier counter (adjacent)
    zero_kernel<<<dim3((2 * HDIM * BATCH + 2 + 255) / 256), 256, 0, stream>>>(hglob, 2 * HDIM * BATCH + 2);

    build_rows<<<1, 256, 0, stream>>>(lengths, rowlist, mact);

    mean_attr_kernel<<<dim3(BATCH), 320, 0, stream>>>(topk, attr_emb, mean_attr);

    zf_kernel<<<dim3(G4 / 256, BATCH), 256, 0, stream>>>(img, mean_attr, Wk, bias, zf);

    gemm_zpreT<<<dim3(G4 / 64, (BATCH * TSEQ) / 64), 256, 0, stream>>>(
        word_emb, seq, Wk, zf, z_preT);

    lstm_persist<<<dim3(NBLK), 256, 0, stream>>>(z_preT, Wk, lengths, hglob, h_seq, bar);

    fill_masked<<<dim3(BATCH * TSEQ), 256, 0, stream>>>(lengths, blog, out_logits);

    gemm_logits<<<dim3(VOCAB / 64, (BATCH * TSEQ) / 64), 256, 0, stream>>>(
        h_seq, rowlist, mact, Wlog, blog, out_logits);

    argmax_kernel<<<dim3(BATCH * TSEQ), 256, 0, stream>>>(out_logits, out_argmax);
}

// Round 3
// 1466.966 us; speedup vs baseline: 2.0833x; 2.0833x over previous
//
#include <hip/hip_runtime.h>
#include <hip/hip_bf16.h>
#include <math.h>

#define BATCH 32
#define TSEQ  64
#define KATTR 5
#define VOCAB 32000
#define DE    300
#define DA    300
#define DI    2048
#define HDIM  512
#define G4    2048            // 4*H
#define WOFF  (DE + DI + DA)  // recurrent rows offset in lstm_kernel

// ---------------------------------------------------------------- utility
__global__ void zero_kernel(float* __restrict__ p, int n) {
    int i = blockIdx.x * blockDim.x + threadIdx.x;
    if (i < n) p[i] = 0.f;
}

// ---------------------------------------------------------------- K1: mean attr embedding
__global__ void mean_attr_kernel(const int* __restrict__ topk,
                                 const float* __restrict__ attr_emb,
                                 float* __restrict__ mean_attr) {
    int b = blockIdx.x;
    int tid = threadIdx.x;
    if (tid < DA) {
        float s = 0.f;
        #pragma unroll
        for (int q = 0; q < KATTR; ++q) {
            int a = topk[b * KATTR + q];
            s += attr_emb[(size_t)a * DA + tid];
        }
        mean_attr[b * DA + tid] = s / (float)KATTR;
    }
}

// ---------------------------------------------------------------- K2: zf[b][j] = bias + img@Wimg + mean_attr@Wattr
__launch_bounds__(256)
__global__ void zf_kernel(const float* __restrict__ img,
                          const float* __restrict__ mean_attr,
                          const float* __restrict__ Wk,
                          const float* __restrict__ bias,
                          float* __restrict__ zf) {
    int b = blockIdx.y;
    int j = blockIdx.x * 256 + threadIdx.x;
    float acc = bias[j];
    const float* wimg = Wk + (size_t)DE * G4 + j;
    const float* irow = img + b * DI;
    #pragma unroll 8
    for (int k = 0; k < DI; ++k) acc += irow[k] * wimg[(size_t)k * G4];
    const float* wattr = Wk + (size_t)(DE + DI) * G4 + j;
    const float* arow = mean_attr + b * DA;
    #pragma unroll 4
    for (int k = 0; k < DA; ++k) acc += arow[k] * wattr[(size_t)k * G4];
    zf[b * G4 + j] = acc;
}

// ---------------------------------------------------------------- Wh reshuffle: Whr[bid][k][jj]  jj = g*2+p, col = g*512 + bid*2 + p
__launch_bounds__(256)
__global__ void whr_kernel(const float* __restrict__ Wk, float* __restrict__ Whr) {
    const int bid = blockIdx.x;
    const int tid = threadIdx.x;
    for (int it = 0; it < 16; ++it) {
        int Q = it * 256 + tid;           // 0..4095
        int k = Q >> 3, jj = Q & 7;
        int g = jj >> 1, p = jj & 1;
        Whr[(size_t)bid * 4096 + Q] = Wk[(size_t)(WOFF + k) * G4 + g * HDIM + bid * 2 + p];
    }
}

// ---------------------------------------------------------------- tiled fp32 GEMM, 64x64x16, 256 thr, 4x4/thread
// PERROW: add = addv[(m>>6)*N + n]; else add = addv[n]
template<bool GATHER, bool PERROW>
__launch_bounds__(256)
__global__ void gemm_tile(const float* __restrict__ A,
                          const int* __restrict__ gidx,
                          const float* __restrict__ Bm,
                          const float* __restrict__ addv,
                          float* __restrict__ C,
                          int M, int N, int K, int lda) {
    __shared__ __align__(16) float As[16][68];
    __shared__ __align__(16) float Bs[16][68];
    const int tid = threadIdx.x;
    const int n0 = blockIdx.x * 64;
    const int m0 = blockIdx.y * 64;
    const int tx = tid & 15, ty = tid >> 4;
    const int ar  = tid >> 2;
    const int akq = (tid & 3) << 2;
    const int bkr = tid >> 4;
    const int bc  = (tid & 15) << 2;

    size_t arow;
    if (GATHER) arow = (size_t)gidx[m0 + ar] * (size_t)lda;
    else        arow = (size_t)(m0 + ar) * (size_t)lda;

    float a00=0,a01=0,a02=0,a03=0, a10=0,a11=0,a12=0,a13=0;
    float a20=0,a21=0,a22=0,a23=0, a30=0,a31=0,a32=0,a33=0;

    for (int k0 = 0; k0 < K; k0 += 16) {
        int ka = k0 + akq;
        float4 av;
        if (ka + 4 <= K) {
            av = *(const float4*)(A + arow + ka);
        } else {
            av.x = (ka + 0 < K) ? A[arow + ka + 0] : 0.f;
            av.y = (ka + 1 < K) ? A[arow + ka + 1] : 0.f;
            av.z = (ka + 2 < K) ? A[arow + ka + 2] : 0.f;
            av.w = (ka + 3 < K) ? A[arow + ka + 3] : 0.f;
        }
        As[akq + 0][ar] = av.x;
        As[akq + 1][ar] = av.y;
        As[akq + 2][ar] = av.z;
        As[akq + 3][ar] = av.w;

        int kb = k0 + bkr;
        float4 bv;
        if (kb < K) bv = *(const float4*)(Bm + (size_t)kb * N + n0 + bc);
        else { bv.x = bv.y = bv.z = bv.w = 0.f; }
        *(float4*)&Bs[bkr][bc] = bv;

        __syncthreads();
        #pragma unroll
        for (int kk = 0; kk < 16; ++kk) {
            const float4 a4 = *(const float4*)&As[kk][ty << 2];
            const float4 b4 = *(const float4*)&Bs[kk][tx << 2];
            a00 += a4.x * b4.x; a01 += a4.x * b4.y; a02 += a4.x * b4.z; a03 += a4.x * b4.w;
            a10 += a4.y * b4.x; a11 += a4.y * b4.y; a12 += a4.y * b4.z; a13 += a4.y * b4.w;
            a20 += a4.z * b4.x; a21 += a4.z * b4.y; a22 += a4.z * b4.z; a23 += a4.z * b4.w;
            a30 += a4.w * b4.x; a31 += a4.w * b4.y; a32 += a4.w * b4.z; a33 += a4.w * b4.w;
        }
        __syncthreads();
    }

    float accs[4][4] = {{a00,a01,a02,a03},{a10,a11,a12,a13},{a20,a21,a22,a23},{a30,a31,a32,a33}};
    const int n = n0 + (tx << 2);
    #pragma unroll
    for (int i = 0; i < 4; ++i) {
        int m = m0 + (ty << 2) + i;
        const float* av2 = PERROW ? (addv + (size_t)(m >> 6) * N) : addv;
        float4 o;
        o.x = accs[i][0] + av2[n + 0];
        o.y = accs[i][1] + av2[n + 1];
        o.z = accs[i][2] + av2[n + 2];
        o.w = accs[i][3] + av2[n + 3];
        *(float4*)(C + (size_t)m * N + n) = o;
    }
}

// ---------------------------------------------------------------- row compaction list
__global__ void build_rows(const int* __restrict__ lengths,
                           int* __restrict__ rowlist, int* __restrict__ mact) {
    __shared__ int len[BATCH];
    __shared__ int off[BATCH + 1];
    int tid = threadIdx.x;
    if (tid < BATCH) len[tid] = lengths[tid];
    __syncthreads();
    if (tid == 0) {
        int s = 0;
        for (int b = 0; b < BATCH; ++b) { off[b] = s; s += len[b]; }
        off[BATCH] = s;
        *mact = s;
    }
    __syncthreads();
    int total = off[BATCH];
    for (int i = tid; i < BATCH * TSEQ; i += 256) {
        int b = i >> 6, t = i & 63;
        if (t < len[b]) rowlist[off[b] + t] = i;
    }
    for (int i = tid; i < BATCH * TSEQ; i += 256) {
        if (i >= total) rowlist[i] = 0;
    }
}

// ---------------------------------------------------------------- one LSTM step, 256 blocks x 256 thr
// block bid owns kouts {bid*2, bid*2+1}; j-cols jj=g*2+p -> g*512 + bid*2 + p.
// h in global [k][b]; per-thread register tile 4b x 4j over a 32-k segment.
__launch_bounds__(256, 1)
__global__ void lstm_step2(const float* __restrict__ z_pre,   // [B*T][2048]
                           const float* __restrict__ Whr,     // [256][512][8]
                           const float* __restrict__ hin,     // [512][32]
                           float* __restrict__ hout,          // [512][32]
                           float* __restrict__ cbuf,          // [512][32]
                           float* __restrict__ h_seq,         // [B*T][512]
                           const int* __restrict__ lengths,
                           int t) {
    __shared__ __align__(16) float hsT[HDIM][36];   // [k][b], stride 36 (144B)
    __shared__ __align__(16) float wsm[HDIM][12];   // [k][jj], stride 12 (48B)
    __shared__ __align__(16) float zp[16 * 260];    // [kseg][tile*16+e], row pad +4
    __shared__ float zfull[BATCH][8];
    const int bid = blockIdx.x;
    const int tid = threadIdx.x;

    // early scalar prefetches for the gate phase (independent of staging)
    float zp4[4] = {0, 0, 0, 0};
    int glen = 0, gb = 0, gkk = 0;
    float c_old = 0.f;
    if (tid < 64) {
        gb = tid & 31;
        int kp = tid >> 5;
        gkk = bid * 2 + kp;
        glen = lengths[gb];
        const float* zr = z_pre + ((size_t)(gb * TSEQ + t)) * G4 + gkk;
        zp4[0] = zr[0 * HDIM];
        zp4[1] = zr[1 * HDIM];
        zp4[2] = zr[2 * HDIM];
        zp4[3] = zr[3 * HDIM];
        c_old = cbuf[gkk * BATCH + gb];
    }

    // stage h: 16384 floats, coalesced float4
    #pragma unroll
    for (int it = 0; it < 16; ++it) {
        int Q = it * 256 + tid;          // quad index; addr = 4Q floats
        int k = Q >> 3, bq = Q & 7;
        float4 v = *(const float4*)(hin + (size_t)Q * 4);
        *(float4*)&hsT[k][bq * 4] = v;
    }
    // stage W slice: 4096 floats contiguous
    const float* wsrc = Whr + (size_t)bid * 4096;
    #pragma unroll
    for (int it = 0; it < 4; ++it) {
        int Q = it * 256 + tid;          // 0..1023
        int k = Q >> 1, jjq = Q & 1;
        float4 v = *(const float4*)(wsrc + (size_t)Q * 4);
        *(float4*)&wsm[k][jjq * 4] = v;
    }
    __syncthreads();

    // compute: thread = (kseg, tile); tile -> 4b x 4j
    {
        const int kseg = tid >> 4;
        const int tile = tid & 15;
        const int b0 = (tile >> 1) << 2;
        const int j0 = (tile & 1) << 2;
        const int kb = kseg << 5;
        float a00=0,a01=0,a02=0,a03=0, a10=0,a11=0,a12=0,a13=0;
        float a20=0,a21=0,a22=0,a23=0, a30=0,a31=0,a32=0,a33=0;
        #pragma unroll 8
        for (int kk = 0; kk < 32; ++kk) {
            const int k = kb + kk;
            const float4 h4 = *(const float4*)&hsT[k][b0];
            const float4 w4 = *(const float4*)&wsm[k][j0];
            a00 += h4.x * w4.x; a01 += h4.x * w4.y; a02 += h4.x * w4.z; a03 += h4.x * w4.w;
            a10 += h4.y * w4.x; a11 += h4.y * w4.y; a12 += h4.y * w4.z; a13 += h4.y * w4.w;
            a20 += h4.z * w4.x; a21 += h4.z * w4.y; a22 += h4.z * w4.z; a23 += h4.z * w4.w;
            a30 += h4.w * w4.x; a31 += h4.w * w4.y; a32 += h4.w * w4.z; a33 += h4.w * w4.w;
        }
        float* zpr = &zp[kseg * 260 + tile * 16];
        *(float4*)(zpr + 0)  = make_float4(a00, a01, a02, a03);
        *(float4*)(zpr + 4)  = make_float4(a10, a11, a12, a13);
        *(float4*)(zpr + 8)  = make_float4(a20, a21, a22, a23);
        *(float4*)(zpr + 12) = make_float4(a30, a31, a32, a33);
    }
    __syncthreads();

    // reduce 16 kseg partials -> zfull[b][jj]
    {
        const int b = tid & 31, jj = tid >> 5;
        const int tile2 = ((b >> 2) << 1) + (jj >> 2);
        const int e = ((b & 3) << 2) + (jj & 3);
        float s = 0.f;
        #pragma unroll
        for (int ks = 0; ks < 16; ++ks) s += zp[ks * 260 + tile2 * 16 + e];
        zfull[b][jj] = s;
    }
    __syncthreads();

    // gate math (wave 0): thread (gb, kp)
    if (tid < 64) {
        const int kp = tid >> 5;
        float zi = zfull[gb][0 * 2 + kp] + zp4[0];
        float zF = zfull[gb][1 * 2 + kp] + zp4[1];
        float zg = zfull[gb][2 * 2 + kp] + zp4[2];
        float zo = zfull[gb][3 * 2 + kp] + zp4[3];
        float si = 1.f / (1.f + expf(-zi));
        float sf = 1.f / (1.f + expf(-zF));
        float so = 1.f / (1.f + expf(-zo));
        float c_new = sf * c_old + si * tanhf(zg);
        float h_new = so * tanhf(c_new);
        cbuf[gkk * BATCH + gb] = c_new;
        hout[gkk * BATCH + gb] = h_new;
        h_seq[((size_t)(gb * TSEQ + t)) * HDIM + gkk] = (t < glen) ? h_new : 0.f;
    }
}

// ---------------------------------------------------------------- fill masked logits rows with bias
__launch_bounds__(256)
__global__ void fill_masked(const int* __restrict__ lengths,
                            const float* __restrict__ blog,
                            float* __restrict__ logits) {
    int row = blockIdx.x;
    int b = row >> 6, t = row & 63;
    if (t < lengths[b]) return;
    float* p = logits + (size_t)row * VOCAB;
    for (int v = threadIdx.x * 4; v < VOCAB; v += 256 * 4) {
        float4 o;
        o.x = blog[v + 0]; o.y = blog[v + 1]; o.z = blog[v + 2]; o.w = blog[v + 3];
        *(float4*)(p + v) = o;
    }
}

// ---------------------------------------------------------------- logits GEMM over compacted rows
__launch_bounds__(256)
__global__ void gemm_logits(const float* __restrict__ A,      // h_seq
                            const int* __restrict__ rowlist,
                            const int* __restrict__ mactp,
                            const float* __restrict__ Bm,     // W_logits
                            const float* __restrict__ blog,
                            float* __restrict__ C) {
    const int Mact = *mactp;
    const int m0 = blockIdx.y * 64;
    if (m0 >= Mact) return;
    __shared__ __align__(16) float As[16][68];
    __shared__ __align__(16) float Bs[16][68];
    const int tid = threadIdx.x;
    const int n0 = blockIdx.x * 64;
    const int tx = tid & 15, ty = tid >> 4;
    const int ar  = tid >> 2;
    const int akq = (tid & 3) << 2;
    const int bkr = tid >> 4;
    const int bc  = (tid & 15) << 2;
    const int K = HDIM, N = VOCAB;

    size_t arow = (size_t)rowlist[m0 + ar] * (size_t)HDIM;

    float a00=0,a01=0,a02=0,a03=0, a10=0,a11=0,a12=0,a13=0;
    float a20=0,a21=0,a22=0,a23=0, a30=0,a31=0,a32=0,a33=0;

    for (int k0 = 0; k0 < K; k0 += 16) {
        float4 av = *(const float4*)(A + arow + k0 + akq);
        As[akq + 0][ar] = av.x;
        As[akq + 1][ar] = av.y;
        As[akq + 2][ar] = av.z;
        As[akq + 3][ar] = av.w;
        float4 bv = *(const float4*)(Bm + (size_t)(k0 + bkr) * N + n0 + bc);
        *(float4*)&Bs[bkr][bc] = bv;
        __syncthreads();
        #pragma unroll
        for (int kk = 0; kk < 16; ++kk) {
            const float4 a4 = *(const float4*)&As[kk][ty << 2];
            const float4 b4 = *(const float4*)&Bs[kk][tx << 2];
            a00 += a4.x * b4.x; a01 += a4.x * b4.y; a02 += a4.x * b4.z; a03 += a4.x * b4.w;
            a10 += a4.y * b4.x; a11 += a4.y * b4.y; a12 += a4.y * b4.z; a13 += a4.y * b4.w;
            a20 += a4.z * b4.x; a21 += a4.z * b4.y; a22 += a4.z * b4.z; a23 += a4.z * b4.w;
            a30 += a4.w * b4.x; a31 += a4.w * b4.y; a32 += a4.w * b4.z; a33 += a4.w * b4.w;
        }
        __syncthreads();
    }

    float accs[4][4] = {{a00,a01,a02,a03},{a10,a11,a12,a13},{a20,a21,a22,a23},{a30,a31,a32,a33}};
    const int n = n0 + (tx << 2);
    #pragma unroll
    for (int i = 0; i < 4; ++i) {
        int m = m0 + (ty << 2) + i;
        if (m < Mact) {
            int rm = rowlist[m];
            float4 o;
            o.x = accs[i][0] + blog[n + 0];
            o.y = accs[i][1] + blog[n + 1];
            o.z = accs[i][2] + blog[n + 2];
            o.w = accs[i][3] + blog[n + 3];
            *(float4*)(C + (size_t)rm * VOCAB + n) = o;
        }
    }
}

// ---------------------------------------------------------------- argmax per row (first occurrence)
__launch_bounds__(256)
__global__ void argmax_kernel(const float* __restrict__ logits, float* __restrict__ outa) {
    const int row = blockIdx.x;
    const int tid = threadIdx.x;
    const float* p = logits + (size_t)row * VOCAB;
    float bv = -INFINITY; int bi = VOCAB;
    for (int v = tid; v < VOCAB; v += 256) {
        float x = p[v];
        if (x > bv) { bv = x; bi = v; }
    }
    __shared__ float sv[256];
    __shared__ int   si[256];
    sv[tid] = bv; si[tid] = bi;
    __syncthreads();
    for (int s = 128; s > 0; s >>= 1) {
        if (tid < s) {
            if (sv[tid + s] > sv[tid] || (sv[tid + s] == sv[tid] && si[tid + s] < si[tid])) {
                sv[tid] = sv[tid + s]; si[tid] = si[tid + s];
            }
        }
        __syncthreads();
    }
    if (tid == 0) outa[row] = (float)si[0];
}

// ---------------------------------------------------------------- launcher
extern "C" void kernel_launch(void* const* d_in, const int* in_sizes, int n_in,
                              void* d_out, int out_size, void* d_ws, size_t ws_size,
                              hipStream_t stream) {
    const int*   topk     = (const int*)d_in[0];
    const float* img      = (const float*)d_in[1];
    const int*   seq      = (const int*)d_in[2];
    const int*   lengths  = (const int*)d_in[3];
    const float* word_emb = (const float*)d_in[4];
    const float* attr_emb = (const float*)d_in[5];
    const float* Wk       = (const float*)d_in[6];
    const float* bias     = (const float*)d_in[7];
    const float* Wlog     = (const float*)d_in[8];
    const float* blog     = (const float*)d_in[9];

    float* out_logits = (float*)d_out;
    float* out_argmax = out_logits + (size_t)BATCH * TSEQ * VOCAB;

    // ws layout (floats): mean_attr | zf | cbuf | hb0 | hb1 | h_seq | Whr | rowlist | mact
    float* ws        = (float*)d_ws;
    float* mean_attr = ws;
    float* zf        = mean_attr + BATCH * DA;              // 9600
    float* cbuf      = zf + BATCH * G4;                     // 65536
    float* hb0       = cbuf + HDIM * BATCH;                 // 16384
    float* hb1       = hb0 + HDIM * BATCH;
    float* h_seq     = hb1 + HDIM * BATCH;
    float* Whr       = h_seq + (size_t)BATCH * TSEQ * HDIM; // 4 MB
    int*   rowlist   = (int*)(Whr + (size_t)256 * 4096);
    int*   mact      = rowlist + BATCH * TSEQ;
    // z_pre [2048 rows][2048 j] staged in d_out's logits region; fully consumed
    // by the scan before fill/logits overwrite it.
    float* z_pre     = out_logits;

    // zero c and h0 (adjacent)
    zero_kernel<<<dim3((2 * HDIM * BATCH + 255) / 256), 256, 0, stream>>>(cbuf, 2 * HDIM * BATCH);

    build_rows<<<1, 256, 0, stream>>>(lengths, rowlist, mact);

    whr_kernel<<<dim3(256), 256, 0, stream>>>(Wk, Whr);

    mean_attr_kernel<<<dim3(BATCH), 320, 0, stream>>>(topk, attr_emb, mean_attr);

    zf_kernel<<<dim3(G4 / 256, BATCH), 256, 0, stream>>>(img, mean_attr, Wk, bias, zf);

    // z_pre[b*T+t][j] = word_emb[seq]@Wx + zf[b][j]
    gemm_tile<true, true><<<dim3(G4 / 64, (BATCH * TSEQ) / 64), 256, 0, stream>>>(
        word_emb, seq, Wk, zf, z_pre, BATCH * TSEQ, G4, DE, DE);

    // sequential scan, one kernel per step
    float* hin = hb0;
    float* hout = hb1;
    for (int t = 0; t < TSEQ; ++t) {
        lstm_step2<<<dim3(256), 256, 0, stream>>>(z_pre, Whr, hin, hout, cbuf, h_seq, lengths, t);
        float* tmp = hin; hin = hout; hout = tmp;
    }

    fill_masked<<<dim3(BATCH * TSEQ), 256, 0, stream>>>(lengths, blog, out_logits);

    gemm_logits<<<dim3(VOCAB / 64, (BATCH * TSEQ) / 64), 256, 0, stream>>>(
        h_seq, rowlist, mact, Wlog, blog, out_logits);

    argmax_kernel<<<dim3(BATCH * TSEQ), 256, 0, stream>>>(out_logits, out_argmax);
}